// Round 7
// baseline (114.722 us; speedup 1.0000x reference)
//
#include <hip/hip_runtime.h>
#include <hip/hip_bf16.h>
#include <stdint.h>
#include <stddef.h>

// ---------- types ----------
typedef short bf16x8 __attribute__((ext_vector_type(8)));   // 8 bf16 (4 VGPRs)
typedef short bf16x4 __attribute__((ext_vector_type(4)));   // 4 bf16 (2 VGPRs)
typedef float f32x4 __attribute__((ext_vector_type(4)));
typedef unsigned short us4 __attribute__((ext_vector_type(4)));

#define MFMA16(a, b, c) __builtin_amdgcn_mfma_f32_16x16x32_bf16((a), (b), (c), 0, 0, 0)

static constexpr int BB = 2, SS = 2048, DD = 1024, HH = 16, HD = 64;
static constexpr int MTOK = BB * SS;  // 4096

union U8 { unsigned int u[4]; bf16x8 v; };

// f32 -> bf16 round-to-nearest-even
__device__ __forceinline__ unsigned short f2bf(float x) {
  unsigned int u = __float_as_uint(x);
  u += 0x7fffu + ((u >> 16) & 1u);
  return (unsigned short)(u >> 16);
}

// pack 2 f32 -> 2 bf16 in one inst (lo -> bits[15:0])
__device__ __forceinline__ unsigned int cvtpk(float lo, float hi) {
  unsigned int r;
  asm("v_cvt_pk_bf16_f32 %0, %1, %2" : "=v"(r) : "v"(lo), "v"(hi));
  return r;
}

// async global->LDS, 16B per lane; LDS dest is wave-uniform base (+lane*16 by HW)
__device__ __forceinline__ void gload16(const void* g, void* l) {
  __builtin_amdgcn_global_load_lds(
      (const __attribute__((address_space(1))) void*)g,
      (__attribute__((address_space(3))) void*)l, 16, 0, 0);
}

// ---------- kernel 1: f32 -> bf16 conversion, WEIGHTS ONLY (4MB f32) ----------
__global__ void cvt_w(const float* __restrict__ Wq, const float* __restrict__ Wk,
                      const float* __restrict__ Wv, const float* __restrict__ Wo,
                      unsigned short* __restrict__ wqkv, unsigned short* __restrict__ wo) {
  const int job = blockIdx.y;
  const float* src;
  unsigned short* dst;
  switch (job) {
    case 0: src = Wq; dst = wqkv;               break;
    case 1: src = Wk; dst = wqkv + DD * DD;     break;
    case 2: src = Wv; dst = wqkv + 2 * DD * DD; break;
    default: src = Wo; dst = wo;                break;
  }
  const int i = (blockIdx.x * 256 + threadIdx.x) * 8;  // 512*256*8 = DD*DD
  const float4 a = *(const float4*)(src + i);
  const float4 b = *(const float4*)(src + i + 4);
  bf16x8 o;
  o[0] = (short)f2bf(a.x); o[1] = (short)f2bf(a.y);
  o[2] = (short)f2bf(a.z); o[3] = (short)f2bf(a.w);
  o[4] = (short)f2bf(b.x); o[5] = (short)f2bf(b.y);
  o[6] = (short)f2bf(b.z); o[7] = (short)f2bf(b.w);
  *(bf16x8*)(dst + i) = o;
}

// ---------- kernel 2: fused QKV projection (R7: f32 A reg-staged + 2-phase dbuf) ----------
// A (activations) read as f32 directly from inputs; converted in-register
// (cvt_pk) and written to XOR-swizzled LDS (slot l&7 of row r holds global
// chunk (l&7)^(r&7)). B (weights bf16) via global_load_lds with pre-swizzled
// source. True 2-phase: stage t+1 issued before compute of t, ONE barrier/iter.
__global__ __launch_bounds__(256, 2) void gemm_qkv(
    const float* __restrict__ qf32, const float* __restrict__ kf32,
    const float* __restrict__ vf32, const unsigned short* __restrict__ wqkv,
    unsigned short* __restrict__ Qh, unsigned short* __restrict__ Kh,
    unsigned short* __restrict__ Vt) {
  __shared__ unsigned short sA[2][128 * 64] __attribute__((aligned(16)));  // 2x16KB
  __shared__ unsigned short sB[2][128 * 64] __attribute__((aligned(16)));  // 2x16KB
  const int lin = blockIdx.x;
  const int swz = (lin & 7) * 96 + (lin >> 3);  // 768 = 8 * 96 (XCD swizzle)
  const int n0 = (swz % 24) * 128, m0 = (swz / 24) * 128;
  const int proj = n0 >> 10;  // 0:Q 1:K 2:V
  const float* A = proj == 0 ? qf32 : (proj == 1 ? kf32 : vf32);
  const int w = threadIdx.x >> 6, l = threadIdx.x & 63;
  const int wr = w >> 1, wc = w & 1, row = l & 15, g4 = l >> 4;
  const int sRow = l >> 3;          // row within 8-row staging group
  const int sCh = (l & 7) ^ sRow;   // fetched global chunk for LDS slot (l&7)
  const float* gA = A + (size_t)(m0 + w * 32 + sRow) * 1024 + sCh * 8;
  const unsigned short* gB = wqkv + (size_t)(n0 + w * 32 + sRow) * 1024 + sCh * 8;
  const int rk = row & 7;           // read-side XOR key

  const f32x4 z = {0.f, 0.f, 0.f, 0.f};
  f32x4 acc[4][4];
#pragma unroll
  for (int i = 0; i < 4; ++i)
#pragma unroll
    for (int j = 0; j < 4; ++j) acc[i][j] = z;

  float4 av[4][2];
#define LOAD_A(T)                                                  \
  _Pragma("unroll") for (int i = 0; i < 4; ++i) {                  \
    const float* p = gA + (size_t)(i * 8) * 1024 + (T) * 64;       \
    av[i][0] = *(const float4*)(p);                                \
    av[i][1] = *(const float4*)(p + 4);                            \
  }
#define WRITE_A(BUF)                                               \
  _Pragma("unroll") for (int i = 0; i < 4; ++i) {                  \
    U8 u;                                                          \
    u.u[0] = cvtpk(av[i][0].x, av[i][0].y);                        \
    u.u[1] = cvtpk(av[i][0].z, av[i][0].w);                        \
    u.u[2] = cvtpk(av[i][1].x, av[i][1].y);                        \
    u.u[3] = cvtpk(av[i][1].z, av[i][1].w);                        \
    *(bf16x8*)(&sA[BUF][(w * 32 + i * 8 + sRow) * 64 + (l & 7) * 8]) = u.v; \
  }
#define STAGE_B(T, BUF)                                            \
  _Pragma("unroll") for (int i = 0; i < 4; ++i)                    \
      gload16(gB + (size_t)(i * 8) * 1024 + (T) * 64,              \
              &sB[BUF][(w * 32 + i * 8) * 64]);

  // prologue: tile 0 into buf 0
  LOAD_A(0)
  STAGE_B(0, 0)
  WRITE_A(0)
  __syncthreads();  // drains B vmcnt; A writes ordered by lgkmcnt+barrier
  int cur = 0;

  for (int t = 0; t < 16; ++t) {
    if (t < 15) {
      LOAD_A(t + 1)          // f32 loads in flight across compute (T14)
      STAGE_B(t + 1, cur ^ 1)  // B direct-to-LDS, drained at end barrier
    }
#pragma unroll
    for (int kk = 0; kk < 2; ++kk) {
      bf16x8 af[4], bfr[4];
      const int ch = ((kk * 4 + g4) ^ rk) << 3;
#pragma unroll
      for (int mi = 0; mi < 4; ++mi)
        af[mi] = *(const bf16x8*)(&sA[cur][(wr * 64 + mi * 16 + row) * 64 + ch]);
#pragma unroll
      for (int ni = 0; ni < 4; ++ni)
        bfr[ni] = *(const bf16x8*)(&sB[cur][(wc * 64 + ni * 16 + row) * 64 + ch]);
#pragma unroll
      for (int mi = 0; mi < 4; ++mi)
#pragma unroll
        for (int ni = 0; ni < 4; ++ni)
          acc[mi][ni] = MFMA16(af[mi], bfr[ni], acc[mi][ni]);
    }
    if (t < 15) WRITE_A(cur ^ 1)
    __syncthreads();  // one barrier/iter: reads of cur done + nb ready next iter
    cur ^= 1;
  }
#undef LOAD_A
#undef WRITE_A
#undef STAGE_B

  // epilogue: Qh,Kh [B,H,S,64]; V transposed Vt [B,H,64,S]
#pragma unroll
  for (int mi = 0; mi < 4; ++mi) {
    const int mbase = m0 + wr * 64 + mi * 16 + g4 * 4;  // token row
    const int bb = mbase >> 11, ss = mbase & 2047;
#pragma unroll
    for (int ni = 0; ni < 4; ++ni) {
      const int c = n0 + wc * 64 + ni * 16 + row;
      const int cc = c & 1023, h = cc >> 6, d = cc & 63;
      if (proj == 0) {
        unsigned short* p = Qh + (((size_t)bb * HH + h) * SS + ss) * HD + d;
#pragma unroll
        for (int r = 0; r < 4; ++r) p[(size_t)r * HD] = f2bf(acc[mi][ni][r]);
      } else if (proj == 1) {
        unsigned short* p = Kh + (((size_t)bb * HH + h) * SS + ss) * HD + d;
#pragma unroll
        for (int r = 0; r < 4; ++r) p[(size_t)r * HD] = f2bf(acc[mi][ni][r]);
      } else {
        us4 pk;
#pragma unroll
        for (int r = 0; r < 4; ++r) pk[r] = f2bf(acc[mi][ni][r]);
        *(us4*)(Vt + (((size_t)bb * HH + h) * HD + d) * SS + ss) = pk;
      }
    }
  }
}

// ---------- kernel 3: causal flash attention (R5 paired version — measured best) ----------
// grid (bh=32, pair=8), 512 thr = 4 q-groups (32 q) x 2 k-halves (64 k).
// Swapped QK^T; P in registers (pi-trick); static-max softmax; k-half partials
// combine by addition at the end (LDS bounce reusing sK/sVT).
__global__ __launch_bounds__(512, 2) void attn_fwd(const unsigned short* __restrict__ Qh,
                                                   const unsigned short* __restrict__ Kh,
                                                   const unsigned short* __restrict__ Vt,
                                                   unsigned short* __restrict__ ctx) {
  __shared__ unsigned short sK[2][128 * 64] __attribute__((aligned(16)));   // 2x16KB
  __shared__ unsigned short sVT[2][64 * 128] __attribute__((aligned(16)));  // 2x16KB
  const int w = threadIdx.x >> 6, l = threadIdx.x & 63;
  const int row = l & 15, g4 = l >> 4;
  const int qg = w & 3, kh = w >> 2;   // q-group, k-half
  const int ko = kh * 64;              // k offset within tile
  const int bh = blockIdx.x, pair = blockIdx.y;
  const size_t bhS = (size_t)bh * SS;
  const int bb = bh >> 4, h = bh & 15;

  const int kLane = l >> 3;            // staging: row-in-group 0..7 (K tile)
  const int kCh = (l & 7) ^ kLane;     // fetched chunk16 (key = row&7)
  const unsigned short* gvBase = Vt + (size_t)bh * HD * SS;

  const f32x4 z = {0.f, 0.f, 0.f, 0.f};
  constexpr float C1 = 0.18033688f;    // 0.125 * log2(e)
  constexpr float C2 = -17.3123405f;   // -12 * log2(e)

  for (int half = 0; half < 2; ++half) {
    const int qi = half ? (15 - pair) : pair;
    const int q0 = qi * 128;
    const int qw = q0 + qg * 32;       // wave's q base (32 rows)

    bf16x8 qf[2][2];
#pragma unroll
    for (int mi = 0; mi < 2; ++mi)
#pragma unroll
      for (int kk = 0; kk < 2; ++kk)
        qf[mi][kk] = *(const bf16x8*)(Qh + (bhS + qw + mi * 16 + row) * HD +
                                      kk * 32 + g4 * 8);

    f32x4 o[2][4];
#pragma unroll
    for (int mi = 0; mi < 2; ++mi)
#pragma unroll
      for (int di = 0; di < 4; ++di) o[mi][di] = z;
    float lsum[2] = {0.f, 0.f};

    // ---- stage tile 0 into buf 0 (all 8 waves; K 16 rows/wave, VT 8 rows/wave) ----
    {
      const unsigned short* gk = Kh + (bhS + 0) * HD;
      const unsigned short* gv = gvBase;
#pragma unroll
      for (int i = 0; i < 2; ++i) {
        const int R = w * 16 + i * 8;
        gload16(gk + (size_t)(R + kLane) * HD + kCh * 8, &sK[0][R * 64]);
      }
#pragma unroll
      for (int i = 0; i < 2; ++i) {
        const int R = w * 8 + i * 4;
        const int vrow = R + g4;
        gload16(gv + (size_t)vrow * SS + ((row ^ (vrow & 15)) * 8), &sVT[0][R * 128]);
      }
    }
    __syncthreads();
    int cur = 0;

    for (int kt = 0; kt <= qi; ++kt) {
      // ---- prefetch next tile into other buffer (in flight across compute) ----
      if (kt < qi) {
        const unsigned short* gk = Kh + (bhS + (kt + 1) * 128) * HD;
        const unsigned short* gv = gvBase + (kt + 1) * 128;
        const int nb = cur ^ 1;
#pragma unroll
        for (int i = 0; i < 2; ++i) {
          const int R = w * 16 + i * 8;
          gload16(gk + (size_t)(R + kLane) * HD + kCh * 8, &sK[nb][R * 64]);
        }
#pragma unroll
        for (int i = 0; i < 2; ++i) {
          const int R = w * 8 + i * 4;
          const int vrow = R + g4;
          gload16(gv + (size_t)vrow * SS + ((row ^ (vrow & 15)) * 8), &sVT[nb][R * 128]);
        }
      }

      // ---- QK^T (swapped): sc[mi][ni]: k = ko+ni*16+4*g4+r, q = qw+mi*16+row ----
      f32x4 sc[2][4];
#pragma unroll
      for (int mi = 0; mi < 2; ++mi)
#pragma unroll
        for (int ni = 0; ni < 4; ++ni) sc[mi][ni] = z;
      __builtin_amdgcn_s_setprio(1);
#pragma unroll
      for (int kk = 0; kk < 2; ++kk)
#pragma unroll
        for (int ni = 0; ni < 4; ++ni) {
          const bf16x8 kf = *(const bf16x8*)(
              &sK[cur][(ko + ni * 16 + row) * 64 + (((kk * 4 + g4) ^ (row & 7)) << 3)]);
          sc[0][ni] = MFMA16(kf, qf[0][kk], sc[0][ni]);
          sc[1][ni] = MFMA16(kf, qf[1][kk], sc[1][ni]);
        }
      __builtin_amdgcn_s_setprio(0);

      // ---- softmax (static max) + in-register P (pi-trick A-frags) ----
      bf16x8 pa[2][2];
      const bool diag = (kt == qi);
#pragma unroll
      for (int mi = 0; mi < 2; ++mi) {
        float ls = 0.f;
        if (!diag) {
#pragma unroll
          for (int kk2 = 0; kk2 < 2; ++kk2) {
            U8 t;
#pragma unroll
            for (int b = 0; b < 2; ++b) {
              const f32x4 s4 = sc[mi][kk2 * 2 + b];
              const float p0 = __builtin_amdgcn_exp2f(fmaf(s4[0], C1, C2));
              const float p1 = __builtin_amdgcn_exp2f(fmaf(s4[1], C1, C2));
              const float p2 = __builtin_amdgcn_exp2f(fmaf(s4[2], C1, C2));
              const float p3 = __builtin_amdgcn_exp2f(fmaf(s4[3], C1, C2));
              ls += (p0 + p1) + (p2 + p3);
              t.u[b * 2 + 0] = cvtpk(p0, p1);
              t.u[b * 2 + 1] = cvtpk(p2, p3);
            }
            pa[mi][kk2] = t.v;
          }
        } else {  // diag tile: mask k > q (relative indices share base kt*128=q0)
          const int relB = ko + 4 * g4 - (qg * 32 + mi * 16 + row);
#pragma unroll
          for (int kk2 = 0; kk2 < 2; ++kk2) {
            U8 t;
#pragma unroll
            for (int b = 0; b < 2; ++b) {
              const f32x4 s4 = sc[mi][kk2 * 2 + b];
              const int base = relB + (kk2 * 2 + b) * 16;
              float t0 = fmaf(s4[0], C1, C2); if (base + 0 > 0) t0 = -1e30f;
              float t1 = fmaf(s4[1], C1, C2); if (base + 1 > 0) t1 = -1e30f;
              float t2 = fmaf(s4[2], C1, C2); if (base + 2 > 0) t2 = -1e30f;
              float t3 = fmaf(s4[3], C1, C2); if (base + 3 > 0) t3 = -1e30f;
              const float p0 = __builtin_amdgcn_exp2f(t0);
              const float p1 = __builtin_amdgcn_exp2f(t1);
              const float p2 = __builtin_amdgcn_exp2f(t2);
              const float p3 = __builtin_amdgcn_exp2f(t3);
              ls += (p0 + p1) + (p2 + p3);
              t.u[b * 2 + 0] = cvtpk(p0, p1);
              t.u[b * 2 + 1] = cvtpk(p2, p3);
            }
            pa[mi][kk2] = t.v;
          }
        }
        lsum[mi] += ls;
      }

      // ---- PV: O[32 q][64 d] += P * V ; vf built per-lane to match pa's k-perm ----
      __builtin_amdgcn_s_setprio(1);
#pragma unroll
      for (int kk2 = 0; kk2 < 2; ++kk2) {
        const int c16a = kh * 8 + kk2 * 4 + (g4 >> 1);  // b=0 chunk16 (global)
        const int c16b = c16a + 2;                      // b=1 chunk16
        const int h8 = (g4 & 1) * 4;                    // 8B half within chunk
#pragma unroll
        for (int di = 0; di < 4; ++di) {
          const int d = di * 16 + row;
          const unsigned short* vr = &sVT[cur][d * 128];
          const bf16x4 vlo = *(const bf16x4*)(vr + ((c16a ^ row) << 3) + h8);
          const bf16x4 vhi = *(const bf16x4*)(vr + ((c16b ^ row) << 3) + h8);
          const bf16x8 vf = __builtin_shufflevector(vlo, vhi, 0, 1, 2, 3, 4, 5, 6, 7);
          o[0][di] = MFMA16(pa[0][kk2], vf, o[0][di]);
          o[1][di] = MFMA16(pa[1][kk2], vf, o[1][di]);
        }
      }
      __builtin_amdgcn_s_setprio(0);
      __syncthreads();  // buffer-reuse fence + drains prefetch
      cur ^= 1;
    }

    // ---- combine k-halves (static max -> pure addition), then write ctx ----
#pragma unroll
    for (int mi = 0; mi < 2; ++mi) {
      lsum[mi] += __shfl_xor(lsum[mi], 16);
      lsum[mi] += __shfl_xor(lsum[mi], 32);  // full sum over this k-half
    }
    f32x4* sO4 = (f32x4*)(&sK[0][0]);        // 2048 slots = 32KB scratch
    float* sL = (float*)(&sVT[0][0]);        // 128 f32: hi-half lsums
    float* sL2 = sL + 128;                   // 128 f32: totals
    if (kh) {
#pragma unroll
      for (int mi = 0; mi < 2; ++mi) {
        if (g4 == 0) sL[(qg * 2 + mi) * 16 + row] = lsum[mi];
#pragma unroll
        for (int di = 0; di < 4; ++di)
          sO4[((qg * 2 + mi) * 4 + g4) * 64 + di * 16 + row] = o[mi][di];
      }
    }
    __syncthreads();
    if (!kh) {
#pragma unroll
      for (int mi = 0; mi < 2; ++mi) {
        const float lt = lsum[mi] + sL[(qg * 2 + mi) * 16 + row];
        if (g4 == 0) sL2[(qg * 2 + mi) * 16 + row] = lt;  // redistribute to PV q-map
      }
#pragma unroll
      for (int mi = 0; mi < 2; ++mi) {
        const f32x4 lv = *(const f32x4*)(sL2 + (qg * 2 + mi) * 16 + g4 * 4);
#pragma unroll
        for (int di = 0; di < 4; ++di) {
          const f32x4 po =
              o[mi][di] + sO4[((qg * 2 + mi) * 4 + g4) * 64 + di * 16 + row];
#pragma unroll
          for (int r = 0; r < 4; ++r) {
            const int ss = qw + mi * 16 + g4 * 4 + r;
            ctx[((size_t)bb * SS + ss) * DD + h * HD + di * 16 + row] =
                f2bf(po[r] * (1.f / lv[r]));
          }
        }
      }
    }
    __syncthreads();  // scratch reads done before next half's staging
  }
}

// ---------- kernel 4: output projection (f32 out), bf16 gload_lds core ----------
__global__ void gemm_out(const unsigned short* __restrict__ ctx,
                         const unsigned short* __restrict__ wo, float* __restrict__ Out) {
  __shared__ unsigned short sA[128 * 64] __attribute__((aligned(16)));
  __shared__ unsigned short sB[128 * 64] __attribute__((aligned(16)));
  const int lin = blockIdx.x;
  const int swz = (lin & 7) * 32 + (lin >> 3);  // 256 = 8 * 32
  const int n0 = (swz % 8) * 128, m0 = (swz / 8) * 128;
  const int w = threadIdx.x >> 6, l = threadIdx.x & 63;
  const int wr = w >> 1, wc = w & 1, row = l & 15, g4 = l >> 4;
  const int sRow = l >> 3, sCh = (l & 7) ^ sRow;
  const unsigned short* ga = ctx + (size_t)(m0 + w * 32 + sRow) * 1024 + sCh * 8;
  const unsigned short* gb = wo + (size_t)(n0 + w * 32 + sRow) * 1024 + sCh * 8;
  unsigned short* la = sA + (w * 32) * 64;
  unsigned short* lb = sB + (w * 32) * 64;
  const int rk = row & 7;
  const f32x4 z = {0.f, 0.f, 0.f, 0.f};
  f32x4 acc[4][4];
#pragma unroll
  for (int i = 0; i < 4; ++i)
#pragma unroll
    for (int j = 0; j < 4; ++j) acc[i][j] = z;
  for (int kt = 0; kt < 1024; kt += 64) {
#pragma unroll
    for (int i = 0; i < 4; ++i) {
      gload16(ga + (size_t)(i * 8) * 1024, la + (i * 8) * 64);
      gload16(gb + (size_t)(i * 8) * 1024, lb + (i * 8) * 64);
    }
    ga += 64;
    gb += 64;
    __syncthreads();
#pragma unroll
    for (int kk = 0; kk < 2; ++kk) {
      bf16x8 af[4], bfr[4];
      const int ch = ((kk * 4 + g4) ^ rk) << 3;
#pragma unroll
      for (int mi = 0; mi < 4; ++mi)
        af[mi] = *(const bf16x8*)(sA + (wr * 64 + mi * 16 + row) * 64 + ch);
#pragma unroll
      for (int ni = 0; ni < 4; ++ni)
        bfr[ni] = *(const bf16x8*)(sB + (wc * 64 + ni * 16 + row) * 64 + ch);
#pragma unroll
      for (int mi = 0; mi < 4; ++mi)
#pragma unroll
        for (int ni = 0; ni < 4; ++ni)
          acc[mi][ni] = MFMA16(af[mi], bfr[ni], acc[mi][ni]);
    }
    __syncthreads();
  }
#pragma unroll
  for (int mi = 0; mi < 4; ++mi) {
    const int mbase = m0 + wr * 64 + mi * 16 + g4 * 4;
#pragma unroll
    for (int ni = 0; ni < 4; ++ni) {
      const int c = n0 + wc * 64 + ni * 16 + row;
      float* p = Out + (size_t)mbase * DD + c;
#pragma unroll
      for (int r = 0; r < 4; ++r) p[(size_t)r * DD] = acc[mi][ni][r];
    }
  }
}

// ---------- launch ----------
extern "C" void kernel_launch(void* const* d_in, const int* in_sizes, int n_in,
                              void* d_out, int out_size, void* d_ws, size_t ws_size,
                              hipStream_t stream) {
  (void)in_sizes; (void)n_in; (void)out_size; (void)ws_size;
  const float* q  = (const float*)d_in[0];
  const float* k  = (const float*)d_in[1];
  const float* v  = (const float*)d_in[2];
  // d_in[3] = causal mask, recomputed analytically
  const float* Wq = (const float*)d_in[4];
  const float* Wk = (const float*)d_in[5];
  const float* Wv = (const float*)d_in[6];
  const float* Wo = (const float*)d_in[7];

  unsigned short* ws = (unsigned short*)d_ws;
  const size_t NTD = (size_t)MTOK * DD;  // 4096*1024
  unsigned short* wqkv = ws;
  unsigned short* wo   = wqkv + (size_t)3 * DD * DD;
  unsigned short* Qh   = wo + (size_t)DD * DD;
  unsigned short* Kh   = Qh + NTD;
  unsigned short* Vt   = Kh + NTD;
  unsigned short* ctx  = Vt + NTD;  // total 40MB of ws

  cvt_w<<<dim3(512, 4), 256, 0, stream>>>(Wq, Wk, Wv, Wo, wqkv, wo);
  gemm_qkv<<<768, 256, 0, stream>>>(q, k, v, wqkv, Qh, Kh, Vt);
  attn_fwd<<<dim3(32, 8), 512, 0, stream>>>(Qh, Kh, Vt, ctx);
  gemm_out<<<256, 256, 0, stream>>>(ctx, wo, (float*)d_out);
}

// Round 8
// 100.344 us; speedup vs baseline: 1.1433x; 1.1433x over previous
//
#include <hip/hip_runtime.h>
#include <hip/hip_bf16.h>
#include <stdint.h>
#include <stddef.h>

// ---------- types ----------
typedef short bf16x8 __attribute__((ext_vector_type(8)));   // 8 bf16 (4 VGPRs)
typedef short bf16x4 __attribute__((ext_vector_type(4)));   // 4 bf16 (2 VGPRs)
typedef float f32x4 __attribute__((ext_vector_type(4)));
typedef unsigned short us4 __attribute__((ext_vector_type(4)));

#define MFMA16(a, b, c) __builtin_amdgcn_mfma_f32_16x16x32_bf16((a), (b), (c), 0, 0, 0)

static constexpr int BB = 2, SS = 2048, DD = 1024, HH = 16, HD = 64;
static constexpr int MTOK = BB * SS;  // 4096

union U8 { unsigned int u[4]; bf16x8 v; };

// f32 -> bf16 round-to-nearest-even
__device__ __forceinline__ unsigned short f2bf(float x) {
  unsigned int u = __float_as_uint(x);
  u += 0x7fffu + ((u >> 16) & 1u);
  return (unsigned short)(u >> 16);
}

// pack 2 f32 -> 2 bf16 in one inst (lo -> bits[15:0])
__device__ __forceinline__ unsigned int cvtpk(float lo, float hi) {
  unsigned int r;
  asm("v_cvt_pk_bf16_f32 %0, %1, %2" : "=v"(r) : "v"(lo), "v"(hi));
  return r;
}

// async global->LDS, 16B per lane; LDS dest is wave-uniform base (+lane*16 by HW)
__device__ __forceinline__ void gload16(const void* g, void* l) {
  __builtin_amdgcn_global_load_lds(
      (const __attribute__((address_space(1))) void*)g,
      (__attribute__((address_space(3))) void*)l, 16, 0, 0);
}

// ---------- kernel 1: f32 -> bf16 conversion, WEIGHTS ONLY (4MB f32) ----------
__global__ void cvt_w(const float* __restrict__ Wq, const float* __restrict__ Wk,
                      const float* __restrict__ Wv, const float* __restrict__ Wo,
                      unsigned short* __restrict__ wqkv, unsigned short* __restrict__ wo) {
  const int job = blockIdx.y;
  const float* src;
  unsigned short* dst;
  switch (job) {
    case 0: src = Wq; dst = wqkv;               break;
    case 1: src = Wk; dst = wqkv + DD * DD;     break;
    case 2: src = Wv; dst = wqkv + 2 * DD * DD; break;
    default: src = Wo; dst = wo;                break;
  }
  const int i = (blockIdx.x * 256 + threadIdx.x) * 8;  // 512*256*8 = DD*DD
  const float4 a = *(const float4*)(src + i);
  const float4 b = *(const float4*)(src + i + 4);
  bf16x8 o;
  o[0] = (short)f2bf(a.x); o[1] = (short)f2bf(a.y);
  o[2] = (short)f2bf(a.z); o[3] = (short)f2bf(a.w);
  o[4] = (short)f2bf(b.x); o[5] = (short)f2bf(b.y);
  o[6] = (short)f2bf(b.z); o[7] = (short)f2bf(b.w);
  *(bf16x8*)(dst + i) = o;
}

// ---------- kernel 2: fused QKV projection (R8) ----------
// R4's proven 2-barrier single-buffer core; A staged as RAW F32 via
// global_load_lds (no cvt pass, no reg round-trip). A row = 256B = 2 halves
// of 8x16B chunks; per-half XOR swizzle slot = c ^ (r&7) (pre-swizzled global
// source). A-frag read: 2x ds_read_b128 + 4x cvt_pk -> bf16x8 (same k-order
// as bf16 path -> operand consistency with B preserved). LDS 48KB -> 3 blk/CU.
__global__ __launch_bounds__(256) void gemm_qkv(
    const float* __restrict__ qf32, const float* __restrict__ kf32,
    const float* __restrict__ vf32, const unsigned short* __restrict__ wqkv,
    unsigned short* __restrict__ Qh, unsigned short* __restrict__ Kh,
    unsigned short* __restrict__ Vt) {
  __shared__ float sAf[128 * 64] __attribute__((aligned(16)));           // 32KB f32
  __shared__ unsigned short sB[128 * 64] __attribute__((aligned(16)));   // 16KB bf16
  const int lin = blockIdx.x;
  const int swz = (lin & 7) * 96 + (lin >> 3);  // 768 = 8 * 96 (XCD swizzle)
  const int n0 = (swz % 24) * 128, m0 = (swz / 24) * 128;
  const int proj = n0 >> 10;  // 0:Q 1:K 2:V
  const float* A = proj == 0 ? qf32 : (proj == 1 ? kf32 : vf32);
  const int w = threadIdx.x >> 6, l = threadIdx.x & 63;
  const int wr = w >> 1, wc = w & 1, row = l & 15, g4 = l >> 4;
  const int rk = row & 7;

  // A staging: wave w covers rows [w*32, w*32+32), 8 gloads x 4 rows (256B row)
  const int aRow = l >> 4;            // row within 4-row group (0..3)
  const int aHalf = (l >> 3) & 1;     // 128B half
  const int aSlot = l & 7;            // chunk slot within half
  const float* gA = A + (size_t)(m0 + w * 32 + aRow) * 1024 + aHalf * 32;
  // B staging: wave w covers rows [w*32,+32), 4 gloads x 8 rows (128B row)
  const int bRow = l >> 3;            // row within 8-row group
  const int bCh = (l & 7) ^ bRow;     // fetched chunk for LDS slot (l&7)
  const unsigned short* gB = wqkv + (size_t)(n0 + w * 32 + bRow) * 1024 + bCh * 8;

  const f32x4 z = {0.f, 0.f, 0.f, 0.f};
  f32x4 acc[4][4];
#pragma unroll
  for (int i = 0; i < 4; ++i)
#pragma unroll
    for (int j = 0; j < 4; ++j) acc[i][j] = z;

  for (int kt = 0; kt < 1024; kt += 64) {
    // ---- stage A (f32, 8 gloads) + B (bf16, 4 gloads) ----
#pragma unroll
    for (int i = 0; i < 8; ++i) {
      const int key = (i * 4 + aRow) & 7;  // per-row swizzle key
      gload16(gA + (size_t)(i * 4) * 1024 + kt + ((aSlot ^ key) * 4),
              &sAf[(w * 32 + i * 4) * 64]);
    }
#pragma unroll
    for (int i = 0; i < 4; ++i)
      gload16(gB + (size_t)(i * 8) * 1024 + kt, &sB[(w * 32 + i * 8) * 64]);
    __syncthreads();  // vmcnt drain -> tiles ready
#pragma unroll
    for (int kk = 0; kk < 2; ++kk) {
      bf16x8 af[4], bfr[4];
      const int ch = ((kk * 4 + g4) ^ rk) << 3;  // B chunk (bf16 units)
#pragma unroll
      for (int mi = 0; mi < 4; ++mi) {
        const float* base = &sAf[(wr * 64 + mi * 16 + row) * 64 + kk * 32];
        const f32x4 a0 = *(const f32x4*)(base + (((2 * g4) ^ rk) * 4));
        const f32x4 a1 = *(const f32x4*)(base + (((2 * g4 + 1) ^ rk) * 4));
        U8 u;
        u.u[0] = cvtpk(a0[0], a0[1]);
        u.u[1] = cvtpk(a0[2], a0[3]);
        u.u[2] = cvtpk(a1[0], a1[1]);
        u.u[3] = cvtpk(a1[2], a1[3]);
        af[mi] = u.v;
      }
#pragma unroll
      for (int ni = 0; ni < 4; ++ni)
        bfr[ni] = *(const bf16x8*)(&sB[(wc * 64 + ni * 16 + row) * 64 + ch]);
#pragma unroll
      for (int mi = 0; mi < 4; ++mi)
#pragma unroll
        for (int ni = 0; ni < 4; ++ni)
          acc[mi][ni] = MFMA16(af[mi], bfr[ni], acc[mi][ni]);
    }
    __syncthreads();  // reads done before next stage
  }

  // epilogue: Qh,Kh [B,H,S,64]; V transposed Vt [B,H,64,S]
#pragma unroll
  for (int mi = 0; mi < 4; ++mi) {
    const int mbase = m0 + wr * 64 + mi * 16 + g4 * 4;  // token row
    const int bb = mbase >> 11, ss = mbase & 2047;
#pragma unroll
    for (int ni = 0; ni < 4; ++ni) {
      const int c = n0 + wc * 64 + ni * 16 + row;
      const int cc = c & 1023, h = cc >> 6, d = cc & 63;
      if (proj == 0) {
        unsigned short* p = Qh + (((size_t)bb * HH + h) * SS + ss) * HD + d;
#pragma unroll
        for (int r = 0; r < 4; ++r) p[(size_t)r * HD] = f2bf(acc[mi][ni][r]);
      } else if (proj == 1) {
        unsigned short* p = Kh + (((size_t)bb * HH + h) * SS + ss) * HD + d;
#pragma unroll
        for (int r = 0; r < 4; ++r) p[(size_t)r * HD] = f2bf(acc[mi][ni][r]);
      } else {
        us4 pk;
#pragma unroll
        for (int r = 0; r < 4; ++r) pk[r] = f2bf(acc[mi][ni][r]);
        *(us4*)(Vt + (((size_t)bb * HH + h) * HD + d) * SS + ss) = pk;
      }
    }
  }
}

// ---------- kernel 3: causal flash attention (R5 paired version — measured best) ----------
__global__ __launch_bounds__(512, 2) void attn_fwd(const unsigned short* __restrict__ Qh,
                                                   const unsigned short* __restrict__ Kh,
                                                   const unsigned short* __restrict__ Vt,
                                                   unsigned short* __restrict__ ctx) {
  __shared__ unsigned short sK[2][128 * 64] __attribute__((aligned(16)));   // 2x16KB
  __shared__ unsigned short sVT[2][64 * 128] __attribute__((aligned(16)));  // 2x16KB
  const int w = threadIdx.x >> 6, l = threadIdx.x & 63;
  const int row = l & 15, g4 = l >> 4;
  const int qg = w & 3, kh = w >> 2;   // q-group, k-half
  const int ko = kh * 64;              // k offset within tile
  const int bh = blockIdx.x, pair = blockIdx.y;
  const size_t bhS = (size_t)bh * SS;
  const int bb = bh >> 4, h = bh & 15;

  const int kLane = l >> 3;            // staging: row-in-group 0..7 (K tile)
  const int kCh = (l & 7) ^ kLane;     // fetched chunk16 (key = row&7)
  const unsigned short* gvBase = Vt + (size_t)bh * HD * SS;

  const f32x4 z = {0.f, 0.f, 0.f, 0.f};
  constexpr float C1 = 0.18033688f;    // 0.125 * log2(e)
  constexpr float C2 = -17.3123405f;   // -12 * log2(e)

  for (int half = 0; half < 2; ++half) {
    const int qi = half ? (15 - pair) : pair;
    const int q0 = qi * 128;
    const int qw = q0 + qg * 32;       // wave's q base (32 rows)

    bf16x8 qf[2][2];
#pragma unroll
    for (int mi = 0; mi < 2; ++mi)
#pragma unroll
      for (int kk = 0; kk < 2; ++kk)
        qf[mi][kk] = *(const bf16x8*)(Qh + (bhS + qw + mi * 16 + row) * HD +
                                      kk * 32 + g4 * 8);

    f32x4 o[2][4];
#pragma unroll
    for (int mi = 0; mi < 2; ++mi)
#pragma unroll
      for (int di = 0; di < 4; ++di) o[mi][di] = z;
    float lsum[2] = {0.f, 0.f};

    // ---- stage tile 0 into buf 0 (all 8 waves; K 16 rows/wave, VT 8 rows/wave) ----
    {
      const unsigned short* gk = Kh + (bhS + 0) * HD;
      const unsigned short* gv = gvBase;
#pragma unroll
      for (int i = 0; i < 2; ++i) {
        const int R = w * 16 + i * 8;
        gload16(gk + (size_t)(R + kLane) * HD + kCh * 8, &sK[0][R * 64]);
      }
#pragma unroll
      for (int i = 0; i < 2; ++i) {
        const int R = w * 8 + i * 4;
        const int vrow = R + g4;
        gload16(gv + (size_t)vrow * SS + ((row ^ (vrow & 15)) * 8), &sVT[0][R * 128]);
      }
    }
    __syncthreads();
    int cur = 0;

    for (int kt = 0; kt <= qi; ++kt) {
      // ---- prefetch next tile into other buffer (in flight across compute) ----
      if (kt < qi) {
        const unsigned short* gk = Kh + (bhS + (kt + 1) * 128) * HD;
        const unsigned short* gv = gvBase + (kt + 1) * 128;
        const int nb = cur ^ 1;
#pragma unroll
        for (int i = 0; i < 2; ++i) {
          const int R = w * 16 + i * 8;
          gload16(gk + (size_t)(R + kLane) * HD + kCh * 8, &sK[nb][R * 64]);
        }
#pragma unroll
        for (int i = 0; i < 2; ++i) {
          const int R = w * 8 + i * 4;
          const int vrow = R + g4;
          gload16(gv + (size_t)vrow * SS + ((row ^ (vrow & 15)) * 8), &sVT[nb][R * 128]);
        }
      }

      // ---- QK^T (swapped): sc[mi][ni]: k = ko+ni*16+4*g4+r, q = qw+mi*16+row ----
      f32x4 sc[2][4];
#pragma unroll
      for (int mi = 0; mi < 2; ++mi)
#pragma unroll
        for (int ni = 0; ni < 4; ++ni) sc[mi][ni] = z;
      __builtin_amdgcn_s_setprio(1);
#pragma unroll
      for (int kk = 0; kk < 2; ++kk)
#pragma unroll
        for (int ni = 0; ni < 4; ++ni) {
          const bf16x8 kf = *(const bf16x8*)(
              &sK[cur][(ko + ni * 16 + row) * 64 + (((kk * 4 + g4) ^ (row & 7)) << 3)]);
          sc[0][ni] = MFMA16(kf, qf[0][kk], sc[0][ni]);
          sc[1][ni] = MFMA16(kf, qf[1][kk], sc[1][ni]);
        }
      __builtin_amdgcn_s_setprio(0);

      // ---- softmax (static max) + in-register P (pi-trick A-frags) ----
      bf16x8 pa[2][2];
      const bool diag = (kt == qi);
#pragma unroll
      for (int mi = 0; mi < 2; ++mi) {
        float ls = 0.f;
        if (!diag) {
#pragma unroll
          for (int kk2 = 0; kk2 < 2; ++kk2) {
            U8 t;
#pragma unroll
            for (int b = 0; b < 2; ++b) {
              const f32x4 s4 = sc[mi][kk2 * 2 + b];
              const float p0 = __builtin_amdgcn_exp2f(fmaf(s4[0], C1, C2));
              const float p1 = __builtin_amdgcn_exp2f(fmaf(s4[1], C1, C2));
              const float p2 = __builtin_amdgcn_exp2f(fmaf(s4[2], C1, C2));
              const float p3 = __builtin_amdgcn_exp2f(fmaf(s4[3], C1, C2));
              ls += (p0 + p1) + (p2 + p3);
              t.u[b * 2 + 0] = cvtpk(p0, p1);
              t.u[b * 2 + 1] = cvtpk(p2, p3);
            }
            pa[mi][kk2] = t.v;
          }
        } else {  // diag tile: mask k > q (relative indices share base kt*128=q0)
          const int relB = ko + 4 * g4 - (qg * 32 + mi * 16 + row);
#pragma unroll
          for (int kk2 = 0; kk2 < 2; ++kk2) {
            U8 t;
#pragma unroll
            for (int b = 0; b < 2; ++b) {
              const f32x4 s4 = sc[mi][kk2 * 2 + b];
              const int base = relB + (kk2 * 2 + b) * 16;
              float t0 = fmaf(s4[0], C1, C2); if (base + 0 > 0) t0 = -1e30f;
              float t1 = fmaf(s4[1], C1, C2); if (base + 1 > 0) t1 = -1e30f;
              float t2 = fmaf(s4[2], C1, C2); if (base + 2 > 0) t2 = -1e30f;
              float t3 = fmaf(s4[3], C1, C2); if (base + 3 > 0) t3 = -1e30f;
              const float p0 = __builtin_amdgcn_exp2f(t0);
              const float p1 = __builtin_amdgcn_exp2f(t1);
              const float p2 = __builtin_amdgcn_exp2f(t2);
              const float p3 = __builtin_amdgcn_exp2f(t3);
              ls += (p0 + p1) + (p2 + p3);
              t.u[b * 2 + 0] = cvtpk(p0, p1);
              t.u[b * 2 + 1] = cvtpk(p2, p3);
            }
            pa[mi][kk2] = t.v;
          }
        }
        lsum[mi] += ls;
      }

      // ---- PV: O[32 q][64 d] += P * V ; vf built per-lane to match pa's k-perm ----
      __builtin_amdgcn_s_setprio(1);
#pragma unroll
      for (int kk2 = 0; kk2 < 2; ++kk2) {
        const int c16a = kh * 8 + kk2 * 4 + (g4 >> 1);  // b=0 chunk16 (global)
        const int c16b = c16a + 2;                      // b=1 chunk16
        const int h8 = (g4 & 1) * 4;                    // 8B half within chunk
#pragma unroll
        for (int di = 0; di < 4; ++di) {
          const int d = di * 16 + row;
          const unsigned short* vr = &sVT[cur][d * 128];
          const bf16x4 vlo = *(const bf16x4*)(vr + ((c16a ^ row) << 3) + h8);
          const bf16x4 vhi = *(const bf16x4*)(vr + ((c16b ^ row) << 3) + h8);
          const bf16x8 vf = __builtin_shufflevector(vlo, vhi, 0, 1, 2, 3, 4, 5, 6, 7);
          o[0][di] = MFMA16(pa[0][kk2], vf, o[0][di]);
          o[1][di] = MFMA16(pa[1][kk2], vf, o[1][di]);
        }
      }
      __builtin_amdgcn_s_setprio(0);
      __syncthreads();  // buffer-reuse fence + drains prefetch
      cur ^= 1;
    }

    // ---- combine k-halves (static max -> pure addition), then write ctx ----
#pragma unroll
    for (int mi = 0; mi < 2; ++mi) {
      lsum[mi] += __shfl_xor(lsum[mi], 16);
      lsum[mi] += __shfl_xor(lsum[mi], 32);  // full sum over this k-half
    }
    f32x4* sO4 = (f32x4*)(&sK[0][0]);        // 2048 slots = 32KB scratch
    float* sL = (float*)(&sVT[0][0]);        // 128 f32: hi-half lsums
    float* sL2 = sL + 128;                   // 128 f32: totals
    if (kh) {
#pragma unroll
      for (int mi = 0; mi < 2; ++mi) {
        if (g4 == 0) sL[(qg * 2 + mi) * 16 + row] = lsum[mi];
#pragma unroll
        for (int di = 0; di < 4; ++di)
          sO4[((qg * 2 + mi) * 4 + g4) * 64 + di * 16 + row] = o[mi][di];
      }
    }
    __syncthreads();
    if (!kh) {
#pragma unroll
      for (int mi = 0; mi < 2; ++mi) {
        const float lt = lsum[mi] + sL[(qg * 2 + mi) * 16 + row];
        if (g4 == 0) sL2[(qg * 2 + mi) * 16 + row] = lt;  // redistribute to PV q-map
      }
#pragma unroll
      for (int mi = 0; mi < 2; ++mi) {
        const f32x4 lv = *(const f32x4*)(sL2 + (qg * 2 + mi) * 16 + g4 * 4);
#pragma unroll
        for (int di = 0; di < 4; ++di) {
          const f32x4 po =
              o[mi][di] + sO4[((qg * 2 + mi) * 4 + g4) * 64 + di * 16 + row];
#pragma unroll
          for (int r = 0; r < 4; ++r) {
            const int ss = qw + mi * 16 + g4 * 4 + r;
            ctx[((size_t)bb * SS + ss) * DD + h * HD + di * 16 + row] =
                f2bf(po[r] * (1.f / lv[r]));
          }
        }
      }
    }
    __syncthreads();  // scratch reads done before next half's staging
  }
}

// ---------- kernel 4: output projection (f32 out), bf16 gload_lds core ----------
__global__ void gemm_out(const unsigned short* __restrict__ ctx,
                         const unsigned short* __restrict__ wo, float* __restrict__ Out) {
  __shared__ unsigned short sA[128 * 64] __attribute__((aligned(16)));
  __shared__ unsigned short sB[128 * 64] __attribute__((aligned(16)));
  const int lin = blockIdx.x;
  const int swz = (lin & 7) * 32 + (lin >> 3);  // 256 = 8 * 32
  const int n0 = (swz % 8) * 128, m0 = (swz / 8) * 128;
  const int w = threadIdx.x >> 6, l = threadIdx.x & 63;
  const int wr = w >> 1, wc = w & 1, row = l & 15, g4 = l >> 4;
  const int sRow = l >> 3, sCh = (l & 7) ^ sRow;
  const unsigned short* ga = ctx + (size_t)(m0 + w * 32 + sRow) * 1024 + sCh * 8;
  const unsigned short* gb = wo + (size_t)(n0 + w * 32 + sRow) * 1024 + sCh * 8;
  unsigned short* la = sA + (w * 32) * 64;
  unsigned short* lb = sB + (w * 32) * 64;
  const int rk = row & 7;
  const f32x4 z = {0.f, 0.f, 0.f, 0.f};
  f32x4 acc[4][4];
#pragma unroll
  for (int i = 0; i < 4; ++i)
#pragma unroll
    for (int j = 0; j < 4; ++j) acc[i][j] = z;
  for (int kt = 0; kt < 1024; kt += 64) {
#pragma unroll
    for (int i = 0; i < 4; ++i) {
      gload16(ga + (size_t)(i * 8) * 1024, la + (i * 8) * 64);
      gload16(gb + (size_t)(i * 8) * 1024, lb + (i * 8) * 64);
    }
    ga += 64;
    gb += 64;
    __syncthreads();
#pragma unroll
    for (int kk = 0; kk < 2; ++kk) {
      bf16x8 af[4], bfr[4];
      const int ch = ((kk * 4 + g4) ^ rk) << 3;
#pragma unroll
      for (int mi = 0; mi < 4; ++mi)
        af[mi] = *(const bf16x8*)(sA + (wr * 64 + mi * 16 + row) * 64 + ch);
#pragma unroll
      for (int ni = 0; ni < 4; ++ni)
        bfr[ni] = *(const bf16x8*)(sB + (wc * 64 + ni * 16 + row) * 64 + ch);
#pragma unroll
      for (int mi = 0; mi < 4; ++mi)
#pragma unroll
        for (int ni = 0; ni < 4; ++ni)
          acc[mi][ni] = MFMA16(af[mi], bfr[ni], acc[mi][ni]);
    }
    __syncthreads();
  }
#pragma unroll
  for (int mi = 0; mi < 4; ++mi) {
    const int mbase = m0 + wr * 64 + mi * 16 + g4 * 4;
#pragma unroll
    for (int ni = 0; ni < 4; ++ni) {
      const int c = n0 + wc * 64 + ni * 16 + row;
      float* p = Out + (size_t)mbase * DD + c;
#pragma unroll
      for (int r = 0; r < 4; ++r) p[(size_t)r * DD] = acc[mi][ni][r];
    }
  }
}

// ---------- launch ----------
extern "C" void kernel_launch(void* const* d_in, const int* in_sizes, int n_in,
                              void* d_out, int out_size, void* d_ws, size_t ws_size,
                              hipStream_t stream) {
  (void)in_sizes; (void)n_in; (void)out_size; (void)ws_size;
  const float* q  = (const float*)d_in[0];
  const float* k  = (const float*)d_in[1];
  const float* v  = (const float*)d_in[2];
  // d_in[3] = causal mask, recomputed analytically
  const float* Wq = (const float*)d_in[4];
  const float* Wk = (const float*)d_in[5];
  const float* Wv = (const float*)d_in[6];
  const float* Wo = (const float*)d_in[7];

  unsigned short* ws = (unsigned short*)d_ws;
  const size_t NTD = (size_t)MTOK * DD;  // 4096*1024
  unsigned short* wqkv = ws;
  unsigned short* wo   = wqkv + (size_t)3 * DD * DD;
  unsigned short* Qh   = wo + (size_t)DD * DD;
  unsigned short* Kh   = Qh + NTD;
  unsigned short* Vt   = Kh + NTD;
  unsigned short* ctx  = Vt + NTD;  // total 40MB of ws

  cvt_w<<<dim3(512, 4), 256, 0, stream>>>(Wq, Wk, Wv, Wo, wqkv, wo);
  gemm_qkv<<<768, 256, 0, stream>>>(q, k, v, wqkv, Qh, Kh, Vt);
  attn_fwd<<<dim3(32, 8), 512, 0, stream>>>(Qh, Kh, Vt, ctx);
  gemm_out<<<256, 256, 0, stream>>>(ctx, wo, (float*)d_out);
}